// Round 1
// baseline (1256.050 us; speedup 1.0000x reference)
//
#include <hip/hip_runtime.h>
#include <cstdint>

#define HD   12     // num heads
#define TSEQ 2048   // sequence length
#define DM   768    // d_model
#define DK   64     // head dim
#define BATCH 2

// ---------------------------------------------------------------------------
// Core NT GEMM tile: C[m][n] = alpha * sum_k A[m][k] * B[n][k]
// 256 threads (4 waves as 2x2), 128x128 tile, BK=8, 8x8 per thread.
// LDS is K-MAJOR (As[kk][m]) so fragment reads are ds_read_b128.
// Row length 132 floats: 16B-aligned row starts (132*4=528=33*16), and the
// 8-float-strided fragment reads alias banks only 2-way (free on CDNA4).
// ---------------------------------------------------------------------------
__device__ __forceinline__ void gemm_nt_core(
    const float* __restrict__ A, const float* __restrict__ B,
    float* __restrict__ C, int m0, int n0, int K,
    int lda, int ldb, int ldc, float alpha)
{
    __shared__ float As[8][132];
    __shared__ float Bs[8][132];

    const int t = threadIdx.x;          // 0..255
    // staging mapping: 2 threads per row, each loads 4 consecutive k (float4)
    const int row = t & 127;
    const int kh4 = (t >> 7) * 4;       // 0 or 4
    const float* Arow = A + (size_t)(m0 + row) * lda + kh4;
    const float* Brow = B + (size_t)(n0 + row) * ldb + kh4;

    // compute mapping: wave (2x2) x lane (8x8), 8x8 outputs per thread
    const int w  = t >> 6;
    const int l  = t & 63;
    const int orow = (w >> 1) * 64 + (l >> 3) * 8;
    const int ocol = (w & 1) * 64 + (l & 7) * 8;

    float acc[8][8];
    #pragma unroll
    for (int i = 0; i < 8; ++i)
        #pragma unroll
        for (int j = 0; j < 8; ++j) acc[i][j] = 0.f;

    for (int k0 = 0; k0 < K; k0 += 8) {
        const float4 av = *(const float4*)(Arow + k0);
        const float4 bv = *(const float4*)(Brow + k0);
        __syncthreads();
        As[kh4 + 0][row] = av.x; As[kh4 + 1][row] = av.y;
        As[kh4 + 2][row] = av.z; As[kh4 + 3][row] = av.w;
        Bs[kh4 + 0][row] = bv.x; Bs[kh4 + 1][row] = bv.y;
        Bs[kh4 + 2][row] = bv.z; Bs[kh4 + 3][row] = bv.w;
        __syncthreads();
        #pragma unroll
        for (int kk = 0; kk < 8; ++kk) {
            const float4 a0 = *(const float4*)&As[kk][orow];
            const float4 a1 = *(const float4*)&As[kk][orow + 4];
            const float4 b0 = *(const float4*)&Bs[kk][ocol];
            const float4 b1 = *(const float4*)&Bs[kk][ocol + 4];
            const float a[8] = {a0.x, a0.y, a0.z, a0.w, a1.x, a1.y, a1.z, a1.w};
            const float b[8] = {b0.x, b0.y, b0.z, b0.w, b1.x, b1.y, b1.z, b1.w};
            #pragma unroll
            for (int i = 0; i < 8; ++i)
                #pragma unroll
                for (int j = 0; j < 8; ++j)
                    acc[i][j] = fmaf(a[i], b[j], acc[i][j]);
        }
    }

    #pragma unroll
    for (int i = 0; i < 8; ++i) {
        float* crow = C + (size_t)(m0 + orow + i) * ldc + n0 + ocol;
        *(float4*)crow = make_float4(acc[i][0] * alpha, acc[i][1] * alpha,
                                     acc[i][2] * alpha, acc[i][3] * alpha);
        *(float4*)(crow + 4) = make_float4(acc[i][4] * alpha, acc[i][5] * alpha,
                                           acc[i][6] * alpha, acc[i][7] * alpha);
    }
}

// ---------------------------------------------------------------------------
// Fused Q/K/V projection: one launch, blockIdx.y selects {q,k,v} matrix.
// grid (4096/128=32, 3*768/128=18), 256 threads.
// ---------------------------------------------------------------------------
__global__ __launch_bounds__(256) void gemm_qkv(
    const float* __restrict__ q, const float* __restrict__ k,
    const float* __restrict__ v,
    const float* __restrict__ Wq, const float* __restrict__ Wk,
    const float* __restrict__ Wv,
    float* __restrict__ Qp, float* __restrict__ Kp, float* __restrict__ Vp)
{
    const int by  = blockIdx.y;
    const int mat = by / 6;          // 0=Q 1=K 2=V
    const int nb  = by % 6;
    const float* A = (mat == 0) ? q  : (mat == 1) ? k  : v;
    const float* B = (mat == 0) ? Wq : (mat == 1) ? Wk : Wv;
    float*       C = (mat == 0) ? Qp : (mat == 1) ? Kp : Vp;
    gemm_nt_core(A, B, C, blockIdx.x * 128, nb * 128, DM, DM, DM, DM, 1.f);
}

// Output projection: out = ctx @ Wo^T. grid (32, 6), 256 threads.
__global__ __launch_bounds__(256) void gemm_out(
    const float* __restrict__ ctx, const float* __restrict__ Wo,
    float* __restrict__ out)
{
    gemm_nt_core(ctx, Wo, out, blockIdx.x * 128, blockIdx.y * 128,
                 DM, DM, DM, DM, 1.f);
}

// ---------------------------------------------------------------------------
// Scores: S[z,q,k] = 0.125 * sum_d Qp[b,q,h*64+d] * Kp[b,k,h*64+d]
// grid (16, 16, 24), 256 threads, 128x128 tile.
// ---------------------------------------------------------------------------
__global__ __launch_bounds__(256) void attn_scores(
    const float* __restrict__ Qp, const float* __restrict__ Kp,
    float* __restrict__ Wt)
{
    const int z = blockIdx.z, b = z / HD, h = z % HD;
    gemm_nt_core(Qp + (size_t)b * TSEQ * DM + h * DK,
                 Kp + (size_t)b * TSEQ * DM + h * DK,
                 Wt + (size_t)z * TSEQ * TSEQ,
                 blockIdx.x * 128, blockIdx.y * 128,
                 DK, DM, DM, TSEQ, 0.125f);
}

// ---------------------------------------------------------------------------
// In-place row softmax over 2048-length rows, float4 loads/stores.
// One block (256 thr) per row; 49152 blocks — pure HBM pass.
// ---------------------------------------------------------------------------
__global__ __launch_bounds__(256) void softmax_rows(float* __restrict__ Wt)
{
    float* p = Wt + (size_t)blockIdx.x * TSEQ;
    const int t = threadIdx.x;
    const float4 va = *(const float4*)(p + t * 4);
    const float4 vb = *(const float4*)(p + 1024 + t * 4);
    float v[8] = {va.x, va.y, va.z, va.w, vb.x, vb.y, vb.z, vb.w};

    float m = -3.4e38f;
    #pragma unroll
    for (int i = 0; i < 8; ++i) m = fmaxf(m, v[i]);
    #pragma unroll
    for (int off = 32; off > 0; off >>= 1) m = fmaxf(m, __shfl_down(m, off));
    __shared__ float redm[4];
    __shared__ float reds[4];
    const int lane = t & 63, wid = t >> 6;
    if (lane == 0) redm[wid] = m;
    __syncthreads();
    m = fmaxf(fmaxf(redm[0], redm[1]), fmaxf(redm[2], redm[3]));

    float s = 0.f;
    #pragma unroll
    for (int i = 0; i < 8; ++i) { v[i] = __expf(v[i] - m); s += v[i]; }
    #pragma unroll
    for (int off = 32; off > 0; off >>= 1) s += __shfl_down(s, off);
    if (lane == 0) reds[wid] = s;
    __syncthreads();
    s = reds[0] + reds[1] + reds[2] + reds[3];
    const float inv = 1.f / s;

    *(float4*)(p + t * 4) =
        make_float4(v[0] * inv, v[1] * inv, v[2] * inv, v[3] * inv);
    *(float4*)(p + 1024 + t * 4) =
        make_float4(v[4] * inv, v[5] * inv, v[6] * inv, v[7] * inv);
}

// ---------------------------------------------------------------------------
// PV: ctx[b,q,h*64+d] = sum_k W[z,q,k] * Vp[b,k,h*64+d]   (NN GEMM, K=2048)
// grid (16, 1, 24), 256 threads, 128(q) x 64(d) tile, BK=16, 8x4 per thread.
// W tile k-major in LDS (b128 fragment reads, conflict-free: oty spans only
// 4 values per wave -> banks {0,8,16,24}); V tile row-major (b128 reads,
// 2-way alias = free).
// ---------------------------------------------------------------------------
__global__ __launch_bounds__(256) void attn_pv(
    const float* __restrict__ Wt, const float* __restrict__ Vp,
    float* __restrict__ ctx)
{
    const int z = blockIdx.z, b = z / HD, h = z % HD;
    const float* A = Wt + (size_t)z * TSEQ * TSEQ;
    const float* V = Vp + (size_t)b * TSEQ * DM + h * DK;

    __shared__ float Ws[16][132];
    __shared__ float Vs[16][68];

    const int t = threadIdx.x;
    const int m0 = blockIdx.x * 128;
    // W staging: 2 threads/row, 8 consecutive k each
    const int arow = t & 127;
    const int kh8  = (t >> 7) * 8;      // 0 or 8
    const float* Arow = A + (size_t)(m0 + arow) * TSEQ + kh8;
    // V staging: 16 rows x (16 threads x float4) = 16x64, coalesced
    const int vr = t >> 4, vc = (t & 15) * 4;
    const float* Vrow = V + (size_t)vr * DM + vc;
    // output mapping: 16 row-groups x 16 col-groups
    const int oty = t >> 4;             // rows oty*8..+7
    const int otx = t & 15;             // cols otx*4..+3

    float acc[8][4];
    #pragma unroll
    for (int i = 0; i < 8; ++i)
        #pragma unroll
        for (int j = 0; j < 4; ++j) acc[i][j] = 0.f;

    for (int k0 = 0; k0 < TSEQ; k0 += 16) {
        const float4 a0 = *(const float4*)(Arow + k0);
        const float4 a1 = *(const float4*)(Arow + k0 + 4);
        const float4 vv = *(const float4*)(Vrow + (size_t)k0 * DM);
        __syncthreads();
        Ws[kh8 + 0][arow] = a0.x; Ws[kh8 + 1][arow] = a0.y;
        Ws[kh8 + 2][arow] = a0.z; Ws[kh8 + 3][arow] = a0.w;
        Ws[kh8 + 4][arow] = a1.x; Ws[kh8 + 5][arow] = a1.y;
        Ws[kh8 + 6][arow] = a1.z; Ws[kh8 + 7][arow] = a1.w;
        *(float4*)&Vs[vr][vc] = vv;
        __syncthreads();
        #pragma unroll
        for (int kk = 0; kk < 16; ++kk) {
            const float4 a0v = *(const float4*)&Ws[kk][oty * 8];
            const float4 a1v = *(const float4*)&Ws[kk][oty * 8 + 4];
            const float4 bv  = *(const float4*)&Vs[kk][otx * 4];
            const float a[8] = {a0v.x, a0v.y, a0v.z, a0v.w,
                                a1v.x, a1v.y, a1v.z, a1v.w};
            const float bb[4] = {bv.x, bv.y, bv.z, bv.w};
            #pragma unroll
            for (int i = 0; i < 8; ++i)
                #pragma unroll
                for (int j = 0; j < 4; ++j)
                    acc[i][j] = fmaf(a[i], bb[j], acc[i][j]);
        }
    }

    float* cbase = ctx + ((size_t)b * TSEQ + m0 + oty * 8) * DM + h * DK + otx * 4;
    #pragma unroll
    for (int i = 0; i < 8; ++i)
        *(float4*)(cbase + (size_t)i * DM) =
            make_float4(acc[i][0], acc[i][1], acc[i][2], acc[i][3]);
}

// ---------------------------------------------------------------------------
extern "C" void kernel_launch(void* const* d_in, const int* in_sizes, int n_in,
                              void* d_out, int out_size, void* d_ws, size_t ws_size,
                              hipStream_t stream)
{
    const float* q  = (const float*)d_in[0];
    const float* k  = (const float*)d_in[1];
    const float* v  = (const float*)d_in[2];
    const float* Wq = (const float*)d_in[3];
    const float* Wk = (const float*)d_in[4];
    const float* Wv = (const float*)d_in[5];
    const float* Wo = (const float*)d_in[6];

    float* out = (float*)d_out;
    const int BT = BATCH * TSEQ;                 // 4096
    float* wts = out + (size_t)BT * DM;          // [B,H,T,T] region of d_out

    // workspace: Qp, Kp, Vp, ctx — 4 x 12.58 MB fp32
    float* Qp  = (float*)d_ws;
    float* Kp  = Qp + (size_t)BT * DM;
    float* Vp  = Kp + (size_t)BT * DM;
    float* ctx = Vp + (size_t)BT * DM;

    gemm_qkv<<<dim3(BT / 128, 18), 256, 0, stream>>>(q, k, v, Wq, Wk, Wv,
                                                     Qp, Kp, Vp);
    attn_scores<<<dim3(TSEQ / 128, TSEQ / 128, BATCH * HD), 256, 0, stream>>>(
        Qp, Kp, wts);
    softmax_rows<<<BATCH * HD * TSEQ, 256, 0, stream>>>(wts);
    attn_pv<<<dim3(TSEQ / 128, 1, BATCH * HD), 256, 0, stream>>>(wts, Vp, ctx);
    gemm_out<<<dim3(BT / 128, DM / 128), 256, 0, stream>>>(ctx, Wo, out);
}

// Round 2
// 1195.977 us; speedup vs baseline: 1.0502x; 1.0502x over previous
//
#include <hip/hip_runtime.h>
#include <cstdint>

#define HD   12     // num heads
#define TSEQ 2048   // sequence length
#define DM   768    // d_model
#define DK   64     // head dim
#define BATCH 2

// ---------------------------------------------------------------------------
// Core NT GEMM tile: C[m][n] = alpha * sum_k (A[m][k] [+ A2[m][k]]) * B[n][k]
// 256 threads (4 waves as 2x2), 128x128 tile, BK=16, 8x8 per thread.
// LDS is K-MAJOR (As[kk][m]) so fragment reads are ds_read_b128.
// Register double-buffer: next tile's global loads are issued right after the
// barrier and consumed at the NEXT iteration's LDS write -> HBM latency hides
// under the ~2000-cycle FMA block.
// Row length 132 floats: 16B-aligned rows; all LDS access is <=2-way (free).
// ---------------------------------------------------------------------------
template<bool SUMA>
__device__ __forceinline__ void gemm_nt_core(
    const float* __restrict__ A, const float* __restrict__ A2,
    const float* __restrict__ B, float* __restrict__ C,
    int m0, int n0, int K, int lda, int ldb, int ldc, float alpha)
{
    __shared__ float As[16][132];
    __shared__ float Bs[16][132];

    const int t = threadIdx.x;          // 0..255
    // staging: 2 threads per row, each loads 8 consecutive k (2x float4)
    const int row = t & 127;
    const int kh8 = (t >> 7) * 8;       // 0 or 8
    const float* Arow = A + (size_t)(m0 + row) * lda + kh8;
    const float* Brow = B + (size_t)(n0 + row) * ldb + kh8;
    const float* A2row = nullptr;
    if (SUMA) A2row = A2 + (size_t)(m0 + row) * lda + kh8;

    // compute mapping: wave (2x2) x lane (8x8), 8x8 outputs per thread
    const int w  = t >> 6;
    const int l  = t & 63;
    const int orow = (w >> 1) * 64 + (l >> 3) * 8;
    const int ocol = (w & 1) * 64 + (l & 7) * 8;

    float acc[8][8];
    #pragma unroll
    for (int i = 0; i < 8; ++i)
        #pragma unroll
        for (int j = 0; j < 8; ++j) acc[i][j] = 0.f;

    // prologue loads (iteration 0)
    float4 a0 = *(const float4*)(Arow);
    float4 a1 = *(const float4*)(Arow + 4);
    float4 b0 = *(const float4*)(Brow);
    float4 b1 = *(const float4*)(Brow + 4);
    float4 c0, c1;
    if (SUMA) { c0 = *(const float4*)(A2row); c1 = *(const float4*)(A2row + 4); }

    for (int k0 = 0; k0 < K; k0 += 16) {
        __syncthreads();
        if (SUMA) {
            a0.x += c0.x; a0.y += c0.y; a0.z += c0.z; a0.w += c0.w;
            a1.x += c1.x; a1.y += c1.y; a1.z += c1.z; a1.w += c1.w;
        }
        As[kh8 + 0][row] = a0.x; As[kh8 + 1][row] = a0.y;
        As[kh8 + 2][row] = a0.z; As[kh8 + 3][row] = a0.w;
        As[kh8 + 4][row] = a1.x; As[kh8 + 5][row] = a1.y;
        As[kh8 + 6][row] = a1.z; As[kh8 + 7][row] = a1.w;
        Bs[kh8 + 0][row] = b0.x; Bs[kh8 + 1][row] = b0.y;
        Bs[kh8 + 2][row] = b0.z; Bs[kh8 + 3][row] = b0.w;
        Bs[kh8 + 4][row] = b1.x; Bs[kh8 + 5][row] = b1.y;
        Bs[kh8 + 6][row] = b1.z; Bs[kh8 + 7][row] = b1.w;
        __syncthreads();
        // prefetch next tile (consumed at next iteration's LDS write)
        if (k0 + 16 < K) {
            a0 = *(const float4*)(Arow + k0 + 16);
            a1 = *(const float4*)(Arow + k0 + 20);
            b0 = *(const float4*)(Brow + k0 + 16);
            b1 = *(const float4*)(Brow + k0 + 20);
            if (SUMA) {
                c0 = *(const float4*)(A2row + k0 + 16);
                c1 = *(const float4*)(A2row + k0 + 20);
            }
        }
        #pragma unroll
        for (int kk = 0; kk < 16; ++kk) {
            const float4 f0 = *(const float4*)&As[kk][orow];
            const float4 f1 = *(const float4*)&As[kk][orow + 4];
            const float4 g0 = *(const float4*)&Bs[kk][ocol];
            const float4 g1 = *(const float4*)&Bs[kk][ocol + 4];
            const float a[8] = {f0.x, f0.y, f0.z, f0.w, f1.x, f1.y, f1.z, f1.w};
            const float b[8] = {g0.x, g0.y, g0.z, g0.w, g1.x, g1.y, g1.z, g1.w};
            #pragma unroll
            for (int i = 0; i < 8; ++i)
                #pragma unroll
                for (int j = 0; j < 8; ++j)
                    acc[i][j] = fmaf(a[i], b[j], acc[i][j]);
        }
    }

    #pragma unroll
    for (int i = 0; i < 8; ++i) {
        float* crow = C + (size_t)(m0 + orow + i) * ldc + n0 + ocol;
        *(float4*)crow = make_float4(acc[i][0] * alpha, acc[i][1] * alpha,
                                     acc[i][2] * alpha, acc[i][3] * alpha);
        *(float4*)(crow + 4) = make_float4(acc[i][4] * alpha, acc[i][5] * alpha,
                                           acc[i][6] * alpha, acc[i][7] * alpha);
    }
}

// ---------------------------------------------------------------------------
// Fused Q/K/V projection: one launch, blockIdx.y selects {q,k,v} matrix.
// grid (4096/128=32, 3*768/128=18), 256 threads.
// ---------------------------------------------------------------------------
__global__ __launch_bounds__(256) void gemm_qkv(
    const float* __restrict__ q, const float* __restrict__ k,
    const float* __restrict__ v,
    const float* __restrict__ Wq, const float* __restrict__ Wk,
    const float* __restrict__ Wv,
    float* __restrict__ Qp, float* __restrict__ Kp, float* __restrict__ Vp)
{
    const int by  = blockIdx.y;
    const int mat = by / 6;          // 0=Q 1=K 2=V
    const int nb  = by % 6;
    const float* A = (mat == 0) ? q  : (mat == 1) ? k  : v;
    const float* B = (mat == 0) ? Wq : (mat == 1) ? Wk : Wv;
    float*       C = (mat == 0) ? Qp : (mat == 1) ? Kp : Vp;
    gemm_nt_core<false>(A, nullptr, B, C, blockIdx.x * 128, nb * 128,
                        DM, DM, DM, DM, 1.f);
}

// Output projection: out = ctx @ Wo^T (optionally summing two partial ctx).
template<bool SUMA>
__global__ __launch_bounds__(256) void gemm_out(
    const float* __restrict__ ctx0, const float* __restrict__ ctx1,
    const float* __restrict__ Wo, float* __restrict__ out)
{
    gemm_nt_core<SUMA>(ctx0, ctx1, Wo, out, blockIdx.x * 128, blockIdx.y * 128,
                       DM, DM, DM, DM, 1.f);
}

// ---------------------------------------------------------------------------
// Scores: S[z,q,k] = 0.125 * sum_d Qp[b,q,h*64+d] * Kp[b,k,h*64+d]
// grid (16, 16, 24), 256 threads, 128x128 tile.
// ---------------------------------------------------------------------------
__global__ __launch_bounds__(256) void attn_scores(
    const float* __restrict__ Qp, const float* __restrict__ Kp,
    float* __restrict__ Wt)
{
    const int z = blockIdx.z, b = z / HD, h = z % HD;
    gemm_nt_core<false>(Qp + (size_t)b * TSEQ * DM + h * DK, nullptr,
                        Kp + (size_t)b * TSEQ * DM + h * DK,
                        Wt + (size_t)z * TSEQ * TSEQ,
                        blockIdx.x * 128, blockIdx.y * 128,
                        DK, DM, DM, TSEQ, 0.125f);
}

// ---------------------------------------------------------------------------
// In-place row softmax over 2048-length rows, float4 loads/stores.
// One block (256 thr) per row; 49152 blocks — pure HBM pass.
// ---------------------------------------------------------------------------
__global__ __launch_bounds__(256) void softmax_rows(float* __restrict__ Wt)
{
    float* p = Wt + (size_t)blockIdx.x * TSEQ;
    const int t = threadIdx.x;
    const float4 va = *(const float4*)(p + t * 4);
    const float4 vb = *(const float4*)(p + 1024 + t * 4);
    float v[8] = {va.x, va.y, va.z, va.w, vb.x, vb.y, vb.z, vb.w};

    float m = -3.4e38f;
    #pragma unroll
    for (int i = 0; i < 8; ++i) m = fmaxf(m, v[i]);
    #pragma unroll
    for (int off = 32; off > 0; off >>= 1) m = fmaxf(m, __shfl_down(m, off));
    __shared__ float redm[4];
    __shared__ float reds[4];
    const int lane = t & 63, wid = t >> 6;
    if (lane == 0) redm[wid] = m;
    __syncthreads();
    m = fmaxf(fmaxf(redm[0], redm[1]), fmaxf(redm[2], redm[3]));

    float s = 0.f;
    #pragma unroll
    for (int i = 0; i < 8; ++i) { v[i] = __expf(v[i] - m); s += v[i]; }
    #pragma unroll
    for (int off = 32; off > 0; off >>= 1) s += __shfl_down(s, off);
    if (lane == 0) reds[wid] = s;
    __syncthreads();
    s = reds[0] + reds[1] + reds[2] + reds[3];
    const float inv = 1.f / s;

    *(float4*)(p + t * 4) =
        make_float4(v[0] * inv, v[1] * inv, v[2] * inv, v[3] * inv);
    *(float4*)(p + 1024 + t * 4) =
        make_float4(v[4] * inv, v[5] * inv, v[6] * inv, v[7] * inv);
}

// ---------------------------------------------------------------------------
// PV: ctx[b,q,h*64+d] = sum_k W[z,q,k] * Vp[b,k,h*64+d]   (NN GEMM)
// grid (16, nsplit, 24): blockIdx.y picks a K-chunk, partial sums go to
// separate ctx buffers (summed in gemm_out's A-load). 768 blocks at nsplit=2
// -> 3 blocks/CU instead of 1.5. Same register-prefetch pipeline as the core.
// 128(q) x 64(d) tile, BK=16, 8x4 per thread. W tile k-major (b128 frag
// reads, conflict-free); V tile row-major (2-way alias = free).
// ---------------------------------------------------------------------------
__global__ __launch_bounds__(256) void attn_pv(
    const float* __restrict__ Wt, const float* __restrict__ Vp,
    float* __restrict__ ctxp, int kchunk)
{
    const int z = blockIdx.z, b = z / HD, h = z % HD;
    const int kbase = blockIdx.y * kchunk;
    float* ctx = ctxp + (size_t)blockIdx.y * (size_t)BATCH * TSEQ * DM;
    const float* A = Wt + (size_t)z * TSEQ * TSEQ + kbase;
    const float* V = Vp + ((size_t)b * TSEQ + kbase) * DM + h * DK;

    __shared__ float Ws[16][132];
    __shared__ float Vs[16][68];

    const int t = threadIdx.x;
    const int m0 = blockIdx.x * 128;
    // W staging: 2 threads/row, 8 consecutive k each
    const int arow = t & 127;
    const int kh8  = (t >> 7) * 8;      // 0 or 8
    const float* Arow = A + (size_t)(m0 + arow) * TSEQ + kh8;
    // V staging: 16 rows x (16 threads x float4) = 16x64, coalesced
    const int vr = t >> 4, vc = (t & 15) * 4;
    const float* Vrow = V + (size_t)vr * DM + vc;
    // output mapping: 16 row-groups x 16 col-groups
    const int oty = t >> 4;             // rows oty*8..+7
    const int otx = t & 15;             // cols otx*4..+3

    float acc[8][4];
    #pragma unroll
    for (int i = 0; i < 8; ++i)
        #pragma unroll
        for (int j = 0; j < 4; ++j) acc[i][j] = 0.f;

    // prologue loads
    float4 a0 = *(const float4*)(Arow);
    float4 a1 = *(const float4*)(Arow + 4);
    float4 vv = *(const float4*)(Vrow);

    for (int k0 = 0; k0 < kchunk; k0 += 16) {
        __syncthreads();
        Ws[kh8 + 0][arow] = a0.x; Ws[kh8 + 1][arow] = a0.y;
        Ws[kh8 + 2][arow] = a0.z; Ws[kh8 + 3][arow] = a0.w;
        Ws[kh8 + 4][arow] = a1.x; Ws[kh8 + 5][arow] = a1.y;
        Ws[kh8 + 6][arow] = a1.z; Ws[kh8 + 7][arow] = a1.w;
        *(float4*)&Vs[vr][vc] = vv;
        __syncthreads();
        // prefetch next tile
        if (k0 + 16 < kchunk) {
            a0 = *(const float4*)(Arow + k0 + 16);
            a1 = *(const float4*)(Arow + k0 + 20);
            vv = *(const float4*)(Vrow + (size_t)(k0 + 16) * DM);
        }
        #pragma unroll
        for (int kk = 0; kk < 16; ++kk) {
            const float4 a0v = *(const float4*)&Ws[kk][oty * 8];
            const float4 a1v = *(const float4*)&Ws[kk][oty * 8 + 4];
            const float4 bv  = *(const float4*)&Vs[kk][otx * 4];
            const float a[8] = {a0v.x, a0v.y, a0v.z, a0v.w,
                                a1v.x, a1v.y, a1v.z, a1v.w};
            const float bb[4] = {bv.x, bv.y, bv.z, bv.w};
            #pragma unroll
            for (int i = 0; i < 8; ++i)
                #pragma unroll
                for (int j = 0; j < 4; ++j)
                    acc[i][j] = fmaf(a[i], bb[j], acc[i][j]);
        }
    }

    float* cbase = ctx + ((size_t)b * TSEQ + m0 + oty * 8) * DM + h * DK + otx * 4;
    #pragma unroll
    for (int i = 0; i < 8; ++i)
        *(float4*)(cbase + (size_t)i * DM) =
            make_float4(acc[i][0], acc[i][1], acc[i][2], acc[i][3]);
}

// ---------------------------------------------------------------------------
extern "C" void kernel_launch(void* const* d_in, const int* in_sizes, int n_in,
                              void* d_out, int out_size, void* d_ws, size_t ws_size,
                              hipStream_t stream)
{
    const float* q  = (const float*)d_in[0];
    const float* k  = (const float*)d_in[1];
    const float* v  = (const float*)d_in[2];
    const float* Wq = (const float*)d_in[3];
    const float* Wk = (const float*)d_in[4];
    const float* Wv = (const float*)d_in[5];
    const float* Wo = (const float*)d_in[6];

    float* out = (float*)d_out;
    const int BT = BATCH * TSEQ;                 // 4096
    float* wts = out + (size_t)BT * DM;          // [B,H,T,T] region of d_out

    // workspace: Qp, Kp, Vp, ctx0 [, ctx1] — each 12.58 MB fp32
    const size_t bufE = (size_t)BT * DM;
    float* Qp   = (float*)d_ws;
    float* Kp   = Qp + bufE;
    float* Vp   = Kp + bufE;
    float* ctx0 = Vp + bufE;
    float* ctx1 = ctx0 + bufE;
    const int nsplit = (ws_size >= 5 * bufE * sizeof(float)) ? 2 : 1;

    gemm_qkv<<<dim3(BT / 128, 18), 256, 0, stream>>>(q, k, v, Wq, Wk, Wv,
                                                     Qp, Kp, Vp);
    attn_scores<<<dim3(TSEQ / 128, TSEQ / 128, BATCH * HD), 256, 0, stream>>>(
        Qp, Kp, wts);
    softmax_rows<<<BATCH * HD * TSEQ, 256, 0, stream>>>(wts);
    attn_pv<<<dim3(TSEQ / 128, nsplit, BATCH * HD), 256, 0, stream>>>(
        wts, Vp, ctx0, TSEQ / nsplit);
    if (nsplit == 2)
        gemm_out<true><<<dim3(BT / 128, DM / 128), 256, 0, stream>>>(
            ctx0, ctx1, Wo, out);
    else
        gemm_out<false><<<dim3(BT / 128, DM / 128), 256, 0, stream>>>(
            ctx0, nullptr, Wo, out);
}